// Round 4
// baseline (345.059 us; speedup 1.0000x reference)
//
#include <hip/hip_runtime.h>
#include <hip/hip_bf16.h>
#include <stdint.h>

#define B_ROWS 4096
#define IN_F   4096
#define OUT_F  4096

// 256x256 tile, K-step 64, 8 waves (512 threads).
#define BM 256
#define BN 256
#define BK 64
#define NKT (IN_F / BK)   // 64 K-tiles

typedef float  f32x4  __attribute__((ext_vector_type(4)));
typedef float  f32x16 __attribute__((ext_vector_type(16)));
typedef short  bf16x8 __attribute__((ext_vector_type(8)));
typedef unsigned short u16x4 __attribute__((ext_vector_type(4)));

#define AS1 __attribute__((address_space(1)))
#define AS3 __attribute__((address_space(3)))

template<int N> struct IC { static constexpr int v = N; };

__device__ __forceinline__ uint16_t f2bf_rne(float f) {
    uint32_t u = __float_as_uint(f);
    uint32_t r = u + 0x7fffu + ((u >> 16) & 1u);
    return (uint16_t)(r >> 16);
}
__device__ __forceinline__ float bf2f(uint16_t h) {
    return __uint_as_float(((uint32_t)h) << 16);
}

// ---------------------------------------------------------------------------
// Fused prep:
//   blocks [0, 4096):      x fp32 -> xb bf16 [b][k]  and xbT bf16 [k][b]
//   blocks [4096, 12288):  w fp32 + mask -> masked bf16 wb (2048 elems/block)
// Mask dtype detected per-block from the first 256 mask words (L2-hot):
// int32 0/1 mask has upper 3 bytes zero in every word; byte mask at 10%
// density trips w.p. 1 - 0.9^768 ~ 1.
// ---------------------------------------------------------------------------
__global__ __launch_bounds__(256) void prep_kernel(
    const float* __restrict__ x, uint16_t* __restrict__ xb, uint16_t* __restrict__ xbT,
    const float* __restrict__ w, const void* __restrict__ mraw, uint16_t* __restrict__ wb)
{
    const int tid = threadIdx.x;
    const int blk = blockIdx.x;

    if (blk < 4096) {
        __shared__ float t[64][65];
        // ---- x conversion + transpose (64x64 tile) ----
        const int r0 = (blk >> 6) * 64;   // batch rows
        const int c0 = (blk & 63) * 64;   // feature cols
        const int lr = tid >> 4;          // 0..15
        const int lc4 = (tid & 15) * 4;   // 0..60

#pragma unroll
        for (int p = 0; p < 4; ++p) {
            const int row = p * 16 + lr;
            float4 v = *(const float4*)(x + (size_t)(r0 + row) * IN_F + c0 + lc4);
            ushort4 o;
            o.x = f2bf_rne(v.x); o.y = f2bf_rne(v.y);
            o.z = f2bf_rne(v.z); o.w = f2bf_rne(v.w);
            *(ushort4*)(xb + (size_t)(r0 + row) * IN_F + c0 + lc4) = o;
            t[row][lc4 + 0] = v.x; t[row][lc4 + 1] = v.y;
            t[row][lc4 + 2] = v.z; t[row][lc4 + 3] = v.w;
        }
        __syncthreads();
#pragma unroll
        for (int p = 0; p < 4; ++p) {
            const int c = p * 16 + lr;    // source col -> dest row
            ushort4 o;
            o.x = f2bf_rne(t[lc4 + 0][c]);
            o.y = f2bf_rne(t[lc4 + 1][c]);
            o.z = f2bf_rne(t[lc4 + 2][c]);
            o.w = f2bf_rne(t[lc4 + 3][c]);
            *(ushort4*)(xbT + (size_t)(c0 + c) * B_ROWS + r0 + lc4) = o;
        }
    } else {
        // ---- w masking + conversion: 8 elems/thread ----
        __shared__ int wflag[4];
        uint32_t mword = ((const uint32_t*)mraw)[tid];           // words 0..255, L2-hot
        unsigned long long bal = __ballot((mword & 0xFFFFFF00u) != 0);
        if ((tid & 63) == 0) wflag[tid >> 6] = (bal != 0ull);
        __syncthreads();
        const int flag = wflag[0] | wflag[1] | wflag[2] | wflag[3];

        const size_t e = ((size_t)(blk - 4096)) * 2048 + (size_t)tid * 8;
        float4 v0 = *(const float4*)(w + e);
        float4 v1 = *(const float4*)(w + e + 4);
        int m[8];
        if (flag) {   // 1-byte bool mask
            uint2 mm = *(const uint2*)((const uint8_t*)mraw + e);
#pragma unroll
            for (int j = 0; j < 4; ++j) m[j]     = (mm.x >> (8 * j)) & 0xff;
#pragma unroll
            for (int j = 0; j < 4; ++j) m[4 + j] = (mm.y >> (8 * j)) & 0xff;
        } else {      // int32 0/1 mask
            const int* mp = (const int*)mraw + e;
            int4 a = *(const int4*)mp;
            int4 b = *(const int4*)(mp + 4);
            m[0] = a.x; m[1] = a.y; m[2] = a.z; m[3] = a.w;
            m[4] = b.x; m[5] = b.y; m[6] = b.z; m[7] = b.w;
        }
        bf16x8 o;
        o[0] = m[0] ? (short)f2bf_rne(v0.x) : (short)0;
        o[1] = m[1] ? (short)f2bf_rne(v0.y) : (short)0;
        o[2] = m[2] ? (short)f2bf_rne(v0.z) : (short)0;
        o[3] = m[3] ? (short)f2bf_rne(v0.w) : (short)0;
        o[4] = m[4] ? (short)f2bf_rne(v1.x) : (short)0;
        o[5] = m[5] ? (short)f2bf_rne(v1.y) : (short)0;
        o[6] = m[6] ? (short)f2bf_rne(v1.z) : (short)0;
        o[7] = m[7] ? (short)f2bf_rne(v1.w) : (short)0;
        *(bf16x8*)(wb + e) = o;
    }
}

__device__ __forceinline__ bf16x8 ds_read128(uint32_t off) {
    bf16x8 r;
    asm volatile("ds_read_b128 %0, %1" : "=v"(r) : "v"(off));
    return r;
}
#define LDSOFF(p) ((uint32_t)(uintptr_t)(AS3 void*)(p))

// ---------------------------------------------------------------------------
// 256x256x64 free-running GEMM, 32x32x16 MFMA, counted-lgkm lookahead.
// C[b,o] = relu( sum_k xb[b,k]*wb[o,k] + bias[o] ) + xbT[rc[o]][b]
//
// R3 post-mortem: 4x lgkmcnt(0)/tile serialized each wave's LDS burst against
// its MFMA cluster (~2280 stall cyc/tile). This version:
//  - 32x32x16 MFMA: same operand bytes, matrix-pipe 2483->2066 cyc/tile,
//    half the MFMA instructions (m119: 2495 vs 2075 TF ceiling).
//  - counted lgkmcnt lookahead: issue B(8)+A0(4)+A1(4); lgkm(4) retires
//    exactly B+A0 (A1 in flight); MFMA mt0 || A2 reads; lgkm(4) -> A1; ...
//    single lgkm(0) at tile end. DS ops retire in-order (no SMEM in flight),
//    so counted waits name exact read groups.
//  - one s_barrier + one vmcnt(0) per K-tile (stages issued a full tile
//    earlier -> drain ~free). setprio(1) around MFMA clusters (T5).
//
// Fragment layouts (32x32x16 bf16): A: lane&31 = row, lane>>5 = k-octet;
// B: lane&31 = col, lane>>5 = k-octet; C/D: col = lane&31,
// row = (reg&3) + 8*(reg>>2) + 4*(lane>>5)  [m74/m101-verified].
//
// LDS halves LINEAR for global_load_lds (rule 21); XOR swizzle on the global
// source and identically on ds_read: 16B-chunk slot s of row r holds global
// k-chunk s^(r&7). Quarter-wave bank analysis: 16 lanes -> 8 chunk-slots,
// 2 lanes/slot = the volume floor (same distribution as the measured-zero
// 16x16 pattern).
// ---------------------------------------------------------------------------
__global__ __launch_bounds__(512, 2) void gemm_kernel(
    const uint16_t* __restrict__ xb, const uint16_t* __restrict__ wb,
    const uint16_t* __restrict__ xbT, const float* __restrict__ bias,
    const int* __restrict__ rc, float* __restrict__ out)
{
    __shared__ alignas(16) uint16_t Abuf[2][2][128 * BK];   // 64 KB
    __shared__ alignas(16) uint16_t Bbuf[2][2][128 * BK];   // 64 KB
    __shared__ float bias_s[BN];
    __shared__ int   rc_s[BN];

    const int tid = threadIdx.x;

    // XCD-aware bijective swizzle: 256 blocks, 8 XCDs.
    const int bid = blockIdx.x;
    const int wg  = (bid & 7) * 32 + (bid >> 3);
    const int row0 = (wg >> 4) * BM;
    const int col0 = (wg & 15) * BN;

    const int wave = tid >> 6, lane = tid & 63;
    const int wm = wave >> 2;          // 0..1 : which 128-row A half
    const int wn = wave & 3;           // 0..3 : 64-col slice
    const int bh = wn >> 1;            // which 128-col B half
    const int l32 = lane & 31;         // fragment row/col
    const int hh  = lane >> 5;         // k-octet select
    const int sw  = lane & 7;          // swizzle key (row&7 == lane&7)

    // Per-lane swizzled k-chunk byte offsets for kg = 0..3.
    uint32_t kswz[4];
#pragma unroll
    for (int kg = 0; kg < 4; ++kg)
        kswz[kg] = (uint32_t)((((kg << 1) | hh) ^ sw) << 4);

    const uint32_t aRowB = (uint32_t)(l32 * 128);
    const uint32_t bRowB = (uint32_t)((((wn & 1) * 64) + l32) * 128);
    const uint32_t aOff0 = LDSOFF(&Abuf[0][wm][0]) + aRowB;
    const uint32_t aOff1 = LDSOFF(&Abuf[1][wm][0]) + aRowB;
    const uint32_t bOff0 = LDSOFF(&Bbuf[0][bh][0]) + bRowB;
    const uint32_t bOff1 = LDSOFF(&Bbuf[1][bh][0]) + bRowB;

    // Staging source (pre-swizzled global address, rule 21):
    // thread's chunk slot = tid&7, row = tid>>3; source k-chunk = slot^(row&7).
    const int srow = tid >> 3;                              // 0..63
    const int ssw  = ((tid & 7) ^ (srow & 7)) << 3;         // element offset
    const uint16_t* pA0 = xb + (size_t)(row0 + srow) * IN_F + ssw;
    const uint16_t* pB0 = wb + (size_t)(col0 + srow) * IN_F + ssw;
    const uint16_t* pA1 = pA0 + (size_t)128 * IN_F;
    const uint16_t* pB1 = pB0 + (size_t)128 * IN_F;

    auto stage = [&](const uint16_t* src, uint16_t* ldsdst, size_t ko) {
        __builtin_amdgcn_global_load_lds((const AS1 void*)(src + ko),
                                         (AS3 void*)(ldsdst + tid * 8), 16, 0, 0);
        __builtin_amdgcn_global_load_lds((const AS1 void*)(src + ko + (size_t)64 * IN_F),
                                         (AS3 void*)(ldsdst + tid * 8 + 4096), 16, 0, 0);
    };

    // bias/rc -> LDS (retired by the t=0 boundary vmcnt(0)).
    if (tid < BN) {
        __builtin_amdgcn_global_load_lds((const AS1 void*)(bias + col0 + tid),
                                         (AS3 void*)(bias_s + tid), 4, 0, 0);
        __builtin_amdgcn_global_load_lds((const AS1 void*)(rc + col0 + tid),
                                         (AS3 void*)(rc_s + tid), 4, 0, 0);
    }

    f32x16 acc[4][2];   // [mt][nt] 32x32 tiles
#pragma unroll
    for (int mt = 0; mt < 4; ++mt)
#pragma unroll
        for (int nt = 0; nt < 2; ++nt)
#pragma unroll
            for (int r = 0; r < 16; ++r)
                acc[mt][nt][r] = 0.f;

    // Prologue: stage tile 0.
    stage(pA0, &Abuf[0][0][0], 0);
    stage(pA1, &Abuf[0][1][0], 0);
    stage(pB0, &Bbuf[0][0][0], 0);
    stage(pB1, &Bbuf[0][1][0], 0);

#define LGKM(n) do { asm volatile("s_waitcnt lgkmcnt(" #n ")" ::: "memory"); \
                     __builtin_amdgcn_sched_barrier(0); } while (0)

    auto tile = [&](auto curc, int t) {
        constexpr int CUR = decltype(curc)::v;
        constexpr int NXT = CUR ^ 1;
        const uint32_t aB = CUR ? aOff1 : aOff0;
        const uint32_t bB = CUR ? bOff1 : bOff0;
        // t = NKT-1 stages one garbage K-tile past the end; lands in adjacent
        // workspace regions, never consumed.
        const size_t koff = (size_t)(t + 1) * BK;

        bf16x8 b[2][4], a0[4], a1[4];

        // ---- tile boundary: the ONLY barrier+vmcnt (stages are ~1 tile old).
        asm volatile("s_waitcnt vmcnt(0)" ::: "memory");
        __builtin_amdgcn_s_barrier();
        __builtin_amdgcn_sched_barrier(0);

        // Issue: B(8), A-stage, A0(4), A1(4), B-stage.
#pragma unroll
        for (int nt = 0; nt < 2; ++nt)
#pragma unroll
            for (int kg = 0; kg < 4; ++kg)
                b[nt][kg] = ds_read128(bB + nt * 4096 + kswz[kg]);
        stage(pA0, &Abuf[NXT][0][0], koff);
        stage(pA1, &Abuf[NXT][1][0], koff);
#pragma unroll
        for (int kg = 0; kg < 4; ++kg) a0[kg] = ds_read128(aB + kswz[kg]);
#pragma unroll
        for (int kg = 0; kg < 4; ++kg) a1[kg] = ds_read128(aB + 4096 + kswz[kg]);
        stage(pB0, &Bbuf[NXT][0][0], koff);
        stage(pB1, &Bbuf[NXT][1][0], koff);

        LGKM(4);   // B + A0 done; A1 in flight
        __builtin_amdgcn_s_setprio(1);
#pragma unroll
        for (int nt = 0; nt < 2; ++nt)
#pragma unroll
            for (int kg = 0; kg < 4; ++kg)
                acc[0][nt] = __builtin_amdgcn_mfma_f32_32x32x16_bf16(a0[kg], b[nt][kg], acc[0][nt], 0, 0, 0);
        __builtin_amdgcn_s_setprio(0);
#pragma unroll
        for (int kg = 0; kg < 4; ++kg) a0[kg] = ds_read128(aB + 2 * 4096 + kswz[kg]);   // mt2

        LGKM(4);   // A1 done; A2 in flight
        __builtin_amdgcn_s_setprio(1);
#pragma unroll
        for (int nt = 0; nt < 2; ++nt)
#pragma unroll
            for (int kg = 0; kg < 4; ++kg)
                acc[1][nt] = __builtin_amdgcn_mfma_f32_32x32x16_bf16(a1[kg], b[nt][kg], acc[1][nt], 0, 0, 0);
        __builtin_amdgcn_s_setprio(0);
#pragma unroll
        for (int kg = 0; kg < 4; ++kg) a1[kg] = ds_read128(aB + 3 * 4096 + kswz[kg]);   // mt3

        LGKM(4);   // A2 done; A3 in flight
        __builtin_amdgcn_s_setprio(1);
#pragma unroll
        for (int nt = 0; nt < 2; ++nt)
#pragma unroll
            for (int kg = 0; kg < 4; ++kg)
                acc[2][nt] = __builtin_amdgcn_mfma_f32_32x32x16_bf16(a0[kg], b[nt][kg], acc[2][nt], 0, 0, 0);
        __builtin_amdgcn_s_setprio(0);

        LGKM(0);   // A3 done
        __builtin_amdgcn_s_setprio(1);
#pragma unroll
        for (int nt = 0; nt < 2; ++nt)
#pragma unroll
            for (int kg = 0; kg < 4; ++kg)
                acc[3][nt] = __builtin_amdgcn_mfma_f32_32x32x16_bf16(a1[kg], b[nt][kg], acc[3][nt], 0, 0, 0);
        __builtin_amdgcn_s_setprio(0);
    };

    for (int tt = 0; tt < NKT; tt += 2) {
        tile(IC<0>{}, tt);
        tile(IC<1>{}, tt + 1);
    }
#undef LGKM

    // Epilogue. C/D: col = lane&31, row = (reg&3) + 8*(reg>>2) + 4*hh.
#pragma unroll
    for (int nt = 0; nt < 2; ++nt) {
        const int lcol = wn * 64 + nt * 32 + l32;
        const int gcol = col0 + lcol;
        const float bv = bias_s[lcol];
        const int   rv = rc_s[lcol];
#pragma unroll
        for (int mt = 0; mt < 4; ++mt) {
#pragma unroll
            for (int g = 0; g < 4; ++g) {
                const int grow0 = row0 + wm * 128 + mt * 32 + g * 8 + hh * 4;
                u16x4 xq = *(const u16x4*)(xbT + (size_t)rv * B_ROWS + grow0);
#pragma unroll
                for (int r = 0; r < 4; ++r) {
                    float v = fmaxf(acc[mt][nt][g * 4 + r] + bv, 0.0f) + bf2f(xq[r]);
                    out[(size_t)(grow0 + r) * OUT_F + gcol] = v;
                }
            }
        }
    }
}

extern "C" void kernel_launch(void* const* d_in, const int* in_sizes, int n_in,
                              void* d_out, int out_size, void* d_ws, size_t ws_size,
                              hipStream_t stream) {
    const float* x    = (const float*)d_in[0];
    const float* w    = (const float*)d_in[1];
    const float* bias = (const float*)d_in[2];
    const void*  mask = (const void*)d_in[3];
    const int*   rc   = (const int*)d_in[4];
    float* out = (float*)d_out;

    uint16_t* xb   = (uint16_t*)d_ws;                      // 32 MB
    uint16_t* wb   = xb  + (size_t)B_ROWS * IN_F;          // 32 MB
    uint16_t* xbT  = wb  + (size_t)OUT_F * IN_F;           // 32 MB

    prep_kernel<<<4096 + 8192, 256, 0, stream>>>(x, xb, xbT, w, mask, wb);

    gemm_kernel<<<dim3((B_ROWS / BM) * (OUT_F / BN)), dim3(512), 0, stream>>>(
        xb, wb, xbT, bias, rc, out);
}

// Round 5
// 337.201 us; speedup vs baseline: 1.0233x; 1.0233x over previous
//
#include <hip/hip_runtime.h>
#include <hip/hip_bf16.h>
#include <stdint.h>

#define B_ROWS 4096
#define IN_F   4096
#define OUT_F  4096

// 256x256 tile, K-step 64, 8 waves (512 threads).
#define BM 256
#define BN 256
#define BK 64
#define NKT (IN_F / BK)   // 64 K-tiles

typedef float  f32x4  __attribute__((ext_vector_type(4)));
typedef short  bf16x8 __attribute__((ext_vector_type(8)));
typedef unsigned short u16x4 __attribute__((ext_vector_type(4)));

#define AS1 __attribute__((address_space(1)))
#define AS3 __attribute__((address_space(3)))

template<int N> struct IC { static constexpr int v = N; };

__device__ __forceinline__ uint16_t f2bf_rne(float f) {
    uint32_t u = __float_as_uint(f);
    uint32_t r = u + 0x7fffu + ((u >> 16) & 1u);
    return (uint16_t)(r >> 16);
}
__device__ __forceinline__ float bf2f(uint16_t h) {
    return __uint_as_float(((uint32_t)h) << 16);
}

// ---------------------------------------------------------------------------
// Fused prep (R4 version — kept unchanged):
//   blocks [0, 4096):      x fp32 -> xb bf16 [b][k]  and xbT bf16 [k][b]
//   blocks [4096, 12288):  w fp32 + mask -> masked bf16 wb (2048 elems/block)
// ---------------------------------------------------------------------------
__global__ __launch_bounds__(256) void prep_kernel(
    const float* __restrict__ x, uint16_t* __restrict__ xb, uint16_t* __restrict__ xbT,
    const float* __restrict__ w, const void* __restrict__ mraw, uint16_t* __restrict__ wb)
{
    const int tid = threadIdx.x;
    const int blk = blockIdx.x;

    if (blk < 4096) {
        __shared__ float t[64][65];
        const int r0 = (blk >> 6) * 64;   // batch rows
        const int c0 = (blk & 63) * 64;   // feature cols
        const int lr = tid >> 4;          // 0..15
        const int lc4 = (tid & 15) * 4;   // 0..60

#pragma unroll
        for (int p = 0; p < 4; ++p) {
            const int row = p * 16 + lr;
            float4 v = *(const float4*)(x + (size_t)(r0 + row) * IN_F + c0 + lc4);
            ushort4 o;
            o.x = f2bf_rne(v.x); o.y = f2bf_rne(v.y);
            o.z = f2bf_rne(v.z); o.w = f2bf_rne(v.w);
            *(ushort4*)(xb + (size_t)(r0 + row) * IN_F + c0 + lc4) = o;
            t[row][lc4 + 0] = v.x; t[row][lc4 + 1] = v.y;
            t[row][lc4 + 2] = v.z; t[row][lc4 + 3] = v.w;
        }
        __syncthreads();
#pragma unroll
        for (int p = 0; p < 4; ++p) {
            const int c = p * 16 + lr;    // source col -> dest row
            ushort4 o;
            o.x = f2bf_rne(t[lc4 + 0][c]);
            o.y = f2bf_rne(t[lc4 + 1][c]);
            o.z = f2bf_rne(t[lc4 + 2][c]);
            o.w = f2bf_rne(t[lc4 + 3][c]);
            *(ushort4*)(xbT + (size_t)(c0 + c) * B_ROWS + r0 + lc4) = o;
        }
    } else {
        __shared__ int wflag[4];
        uint32_t mword = ((const uint32_t*)mraw)[tid];           // words 0..255, L2-hot
        unsigned long long bal = __ballot((mword & 0xFFFFFF00u) != 0);
        if ((tid & 63) == 0) wflag[tid >> 6] = (bal != 0ull);
        __syncthreads();
        const int flag = wflag[0] | wflag[1] | wflag[2] | wflag[3];

        const size_t e = ((size_t)(blk - 4096)) * 2048 + (size_t)tid * 8;
        float4 v0 = *(const float4*)(w + e);
        float4 v1 = *(const float4*)(w + e + 4);
        int m[8];
        if (flag) {   // 1-byte bool mask
            uint2 mm = *(const uint2*)((const uint8_t*)mraw + e);
#pragma unroll
            for (int j = 0; j < 4; ++j) m[j]     = (mm.x >> (8 * j)) & 0xff;
#pragma unroll
            for (int j = 0; j < 4; ++j) m[4 + j] = (mm.y >> (8 * j)) & 0xff;
        } else {      // int32 0/1 mask
            const int* mp = (const int*)mraw + e;
            int4 a = *(const int4*)mp;
            int4 b = *(const int4*)(mp + 4);
            m[0] = a.x; m[1] = a.y; m[2] = a.z; m[3] = a.w;
            m[4] = b.x; m[5] = b.y; m[6] = b.z; m[7] = b.w;
        }
        bf16x8 o;
        o[0] = m[0] ? (short)f2bf_rne(v0.x) : (short)0;
        o[1] = m[1] ? (short)f2bf_rne(v0.y) : (short)0;
        o[2] = m[2] ? (short)f2bf_rne(v0.z) : (short)0;
        o[3] = m[3] ? (short)f2bf_rne(v0.w) : (short)0;
        o[4] = m[4] ? (short)f2bf_rne(v1.x) : (short)0;
        o[5] = m[5] ? (short)f2bf_rne(v1.y) : (short)0;
        o[6] = m[6] ? (short)f2bf_rne(v1.z) : (short)0;
        o[7] = m[7] ? (short)f2bf_rne(v1.w) : (short)0;
        *(bf16x8*)(wb + e) = o;
    }
}

__device__ __forceinline__ bf16x8 ds_read128(uint32_t off) {
    bf16x8 r;
    asm volatile("ds_read_b128 %0, %1" : "=v"(r) : "v"(off));
    return r;
}
#define LDSOFF(p) ((uint32_t)(uintptr_t)(AS3 void*)(p))

// ---------------------------------------------------------------------------
// 256x256x64 free-running GEMM — R3 structure (16x16x32 MFMA, verified
// conflict-free LDS addressing) + counted-lgkmcnt lookahead.
// C[b,o] = relu( sum_k xb[b,k]*wb[o,k] + bias[o] ) + xbT[rc[o]][b]
//
// R4 post-mortem: the 32x32 read pattern hit 1.26e7 bank conflicts (model
// said equivalent; hardware disagreed) -> reverted to the R3 pattern which
// measured ZERO across R1-R3. Schedule change only (no address changes):
//
//   issue {B,A0,A1}(12 ds_reads); stage A(t+1)
//   lgkm(4)  -> B+A0 ready          | MFMA blk0 (mi0-3,ks0)  | A1 in flight
//   issue A2; stage B(t+1)
//   lgkm(4)  -> A1 ready            | MFMA blk1 (mi4-7,ks0)  | A2 in flight
//   issue {B',A3}
//   lgkm(4)  -> A2+B' ready         | MFMA blk2 (mi0-3,ks1)  | A3 in flight
//   lgkm(0)  -> A3 ready            | MFMA blk3 (mi4-7,ks1)
//
// DS ops retire in-order; stages count on vmcnt (not lgkm), so counted
// waits name exact read groups. One vmcnt(0)+s_barrier per K-tile (stages
// are a full tile old -> drain ~free). setprio(1) around MFMA (T5).
// sched_barrier(0) after each wait (rule 18).
// ---------------------------------------------------------------------------
__global__ __launch_bounds__(512, 2) void gemm_kernel(
    const uint16_t* __restrict__ xb, const uint16_t* __restrict__ wb,
    const uint16_t* __restrict__ xbT, const float* __restrict__ bias,
    const int* __restrict__ rc, float* __restrict__ out)
{
    __shared__ alignas(16) uint16_t Abuf[2][2][128 * BK];   // 64 KB
    __shared__ alignas(16) uint16_t Bbuf[2][2][128 * BK];   // 64 KB
    __shared__ float bias_s[BN];
    __shared__ int   rc_s[BN];

    const int tid = threadIdx.x;

    // XCD-aware bijective swizzle: 256 blocks, 8 XCDs.
    const int bid = blockIdx.x;
    const int wg  = (bid & 7) * 32 + (bid >> 3);
    const int row0 = (wg >> 4) * BM;
    const int col0 = (wg & 15) * BN;

    const int wave = tid >> 6, lane = tid & 63;
    const int wm = wave >> 2;          // 0..1 : which 128-row A half
    const int wn = wave & 3;           // 0..3 : 64-col slice
    const int bh = wn >> 1;            // which 128-col B half
    const int quad = lane >> 4, l16 = lane & 15;
    const int swr = (l16 & 7) << 3;
    const int e0  = (quad << 3) ^ swr;                    // elem offset, ks=0
    const uint32_t kd = (uint32_t)(((e0 ^ 32) - e0) * 2); // byte delta ks0->ks1

    const uint32_t aOff0 = LDSOFF(&Abuf[0][wm][0]) + (uint32_t)((l16 * BK + e0) * 2);
    const uint32_t aOff1 = LDSOFF(&Abuf[1][wm][0]) + (uint32_t)((l16 * BK + e0) * 2);
    const uint32_t bOff0 = LDSOFF(&Bbuf[0][bh][0]) + (uint32_t)((((wn & 1) * 64 + l16) * BK + e0) * 2);
    const uint32_t bOff1 = LDSOFF(&Bbuf[1][bh][0]) + (uint32_t)((((wn & 1) * 64 + l16) * BK + e0) * 2);

    // Staging source (pre-swizzled global address, rule 21):
    // thread's chunk slot = tid&7, row = tid>>3; source k-chunk = slot^(row&7).
    const int srow = tid >> 3;                              // 0..63
    const int ssw  = ((tid & 7) ^ (srow & 7)) << 3;         // element offset
    const uint16_t* pA0 = xb + (size_t)(row0 + srow) * IN_F + ssw;
    const uint16_t* pB0 = wb + (size_t)(col0 + srow) * IN_F + ssw;
    const uint16_t* pA1 = pA0 + (size_t)128 * IN_F;
    const uint16_t* pB1 = pB0 + (size_t)128 * IN_F;

    auto stage = [&](const uint16_t* src, uint16_t* ldsdst, size_t ko) {
        __builtin_amdgcn_global_load_lds((const AS1 void*)(src + ko),
                                         (AS3 void*)(ldsdst + tid * 8), 16, 0, 0);
        __builtin_amdgcn_global_load_lds((const AS1 void*)(src + ko + (size_t)64 * IN_F),
                                         (AS3 void*)(ldsdst + tid * 8 + 4096), 16, 0, 0);
    };

    // bias/rc -> LDS (retired by the t=0 boundary vmcnt(0)).
    if (tid < BN) {
        __builtin_amdgcn_global_load_lds((const AS1 void*)(bias + col0 + tid),
                                         (AS3 void*)(bias_s + tid), 4, 0, 0);
        __builtin_amdgcn_global_load_lds((const AS1 void*)(rc + col0 + tid),
                                         (AS3 void*)(rc_s + tid), 4, 0, 0);
    }

    f32x4 acc[8][4];   // [mi][ni]
#pragma unroll
    for (int mi = 0; mi < 8; ++mi)
#pragma unroll
        for (int ni = 0; ni < 4; ++ni)
            acc[mi][ni] = (f32x4){0.f, 0.f, 0.f, 0.f};

    // Prologue: stage tile 0.
    stage(pA0, &Abuf[0][0][0], 0);
    stage(pA1, &Abuf[0][1][0], 0);
    stage(pB0, &Bbuf[0][0][0], 0);
    stage(pB1, &Bbuf[0][1][0], 0);

#define LGKM(n) do { asm volatile("s_waitcnt lgkmcnt(" #n ")" ::: "memory"); \
                     __builtin_amdgcn_sched_barrier(0); } while (0)

    auto tile = [&](auto curc, int t) {
        constexpr int CUR = decltype(curc)::v;
        constexpr int NXT = CUR ^ 1;
        const uint32_t aB = CUR ? aOff1 : aOff0;
        const uint32_t bB = CUR ? bOff1 : bOff0;
        // t = NKT-1 stages one garbage K-tile past the end; lands in adjacent
        // workspace regions, never consumed.
        const size_t koff = (size_t)(t + 1) * BK;

        bf16x8 b[4], b2[4], a0[4], a1[4], a2[4], a3[4];

        // ---- tile boundary: the ONLY barrier+vmcnt of the tile.
        asm volatile("s_waitcnt vmcnt(0)" ::: "memory");
        __builtin_amdgcn_s_barrier();
        __builtin_amdgcn_sched_barrier(0);

        // ---- issue group 1: B(ks0) + A(ks0, mi0-3) + A(ks0, mi4-7)
#pragma unroll
        for (int ni = 0; ni < 4; ++ni) b[ni]  = ds_read128(bB + ni * 2048);
#pragma unroll
        for (int m = 0; m < 4; ++m)    a0[m]  = ds_read128(aB + m * 2048);
#pragma unroll
        for (int m = 0; m < 4; ++m)    a1[m]  = ds_read128(aB + (4 + m) * 2048);
        stage(pA0, &Abuf[NXT][0][0], koff);
        stage(pA1, &Abuf[NXT][1][0], koff);

        LGKM(4);   // b + a0 ready; a1 in flight
        __builtin_amdgcn_s_setprio(1);
#pragma unroll
        for (int m = 0; m < 4; ++m)
#pragma unroll
            for (int ni = 0; ni < 4; ++ni)
                acc[m][ni] = __builtin_amdgcn_mfma_f32_16x16x32_bf16(a0[m], b[ni], acc[m][ni], 0, 0, 0);
        __builtin_amdgcn_s_setprio(0);

        // ---- issue group 2: A(ks1, mi0-3)
#pragma unroll
        for (int m = 0; m < 4; ++m)    a2[m]  = ds_read128(aB + m * 2048 + kd);
        stage(pB0, &Bbuf[NXT][0][0], koff);
        stage(pB1, &Bbuf[NXT][1][0], koff);

        LGKM(4);   // a1 ready; a2 in flight
        __builtin_amdgcn_s_setprio(1);
#pragma unroll
        for (int m = 0; m < 4; ++m)
#pragma unroll
            for (int ni = 0; ni < 4; ++ni)
                acc[4 + m][ni] = __builtin_amdgcn_mfma_f32_16x16x32_bf16(a1[m], b[ni], acc[4 + m][ni], 0, 0, 0);
        __builtin_amdgcn_s_setprio(0);

        // ---- issue group 3: B(ks1) + A(ks1, mi4-7)
#pragma unroll
        for (int ni = 0; ni < 4; ++ni) b2[ni] = ds_read128(bB + ni * 2048 + kd);
#pragma unroll
        for (int m = 0; m < 4; ++m)    a3[m]  = ds_read128(aB + (4 + m) * 2048 + kd);

        LGKM(4);   // a2 + b2 ready; a3 in flight
        __builtin_amdgcn_s_setprio(1);
#pragma unroll
        for (int m = 0; m < 4; ++m)
#pragma unroll
            for (int ni = 0; ni < 4; ++ni)
                acc[m][ni] = __builtin_amdgcn_mfma_f32_16x16x32_bf16(a2[m], b2[ni], acc[m][ni], 0, 0, 0);
        __builtin_amdgcn_s_setprio(0);

        LGKM(0);   // a3 ready
        __builtin_amdgcn_s_setprio(1);
#pragma unroll
        for (int m = 0; m < 4; ++m)
#pragma unroll
            for (int ni = 0; ni < 4; ++ni)
                acc[4 + m][ni] = __builtin_amdgcn_mfma_f32_16x16x32_bf16(a3[m], b2[ni], acc[4 + m][ni], 0, 0, 0);
        __builtin_amdgcn_s_setprio(0);
    };

    for (int tt = 0; tt < NKT; tt += 2) {
        tile(IC<0>{}, tt);
        tile(IC<1>{}, tt + 1);
    }
#undef LGKM

    // Epilogue. C/D layout: col = lane&15, row = quad*4 + reg (m89-verified).
#pragma unroll
    for (int ni = 0; ni < 4; ++ni) {
        const int lcol = wn * 64 + ni * 16 + l16;
        const int gcol = col0 + lcol;
        const float bv = bias_s[lcol];
        const int   rv = rc_s[lcol];
#pragma unroll
        for (int mi = 0; mi < 8; ++mi) {
            const int grow0 = row0 + wm * 128 + mi * 16 + quad * 4;
            u16x4 xq = *(const u16x4*)(xbT + (size_t)rv * B_ROWS + grow0);
#pragma unroll
            for (int r = 0; r < 4; ++r) {
                float v = fmaxf(acc[mi][ni][r] + bv, 0.0f) + bf2f(xq[r]);
                out[(size_t)(grow0 + r) * OUT_F + gcol] = v;
            }
        }
    }
}

extern "C" void kernel_launch(void* const* d_in, const int* in_sizes, int n_in,
                              void* d_out, int out_size, void* d_ws, size_t ws_size,
                              hipStream_t stream) {
    const float* x    = (const float*)d_in[0];
    const float* w    = (const float*)d_in[1];
    const float* bias = (const float*)d_in[2];
    const void*  mask = (const void*)d_in[3];
    const int*   rc   = (const int*)d_in[4];
    float* out = (float*)d_out;

    uint16_t* xb   = (uint16_t*)d_ws;                      // 32 MB
    uint16_t* wb   = xb  + (size_t)B_ROWS * IN_F;          // 32 MB
    uint16_t* xbT  = wb  + (size_t)OUT_F * IN_F;           // 32 MB

    prep_kernel<<<4096 + 8192, 256, 0, stream>>>(x, xb, xbT, w, mask, wb);

    gemm_kernel<<<dim3((B_ROWS / BM) * (OUT_F / BN)), dim3(512), 0, stream>>>(
        xb, wb, xbT, bias, rc, out);
}